// Round 1
// 230.229 us; speedup vs baseline: 1.1061x; 1.1061x over previous
//
#include <hip/hip_runtime.h>
#include <hip/hip_bf16.h>

#define NB   8
#define NS   5
#define NQ   128
#define TT   16
#define DD   2048
#define NROW 1024               // B*nq
#define NSROW (NB * NS * TT)    // 640 supp rows
#define LDB  1032               // B-tile LDS row stride in shorts (half-K tile, +8 pad)
#define LAMI 10.0f
#define LAMF 0.1f

typedef __attribute__((ext_vector_type(8))) short  short8;
typedef __attribute__((ext_vector_type(4))) float  float4v;

// pack two f32 -> bf16x2 (RNE)
static __device__ __forceinline__ unsigned int f2bf2(float x, float y) {
    union { float f; unsigned int u; } a, b; a.f = x; b.f = y;
    unsigned int ra = a.u + 0x7fffu + ((a.u >> 16) & 1u);
    unsigned int rb = b.u + 0x7fffu + ((b.u >> 16) & 1u);
    return (ra >> 16) | (rb & 0xffff0000u);
}

static __device__ __forceinline__ float lse2f(float x, float y) {
    float mx = fmaxf(x, y), mn = fminf(x, y);
    return mx + __logf(1.0f + __expf(mn - mx));
}

// supp only: f32 -> bf16 + row sum-of-squares. One wave per row (640 rows).
// Block 0 thread 0 also zeroes the loss accumulator (same-stream ordering makes
// it visible to dist_dtw's atomics).
__global__ __launch_bounds__(256) void
preproc_supp(const float* __restrict__ supp, unsigned short* __restrict__ suppBf,
             float* __restrict__ suppSq, float* __restrict__ loss0)
{
    if (blockIdx.x == 0 && threadIdx.x == 0) loss0[0] = 0.f;
    const int wave = threadIdx.x >> 6, lane = threadIdx.x & 63;
    const int row = blockIdx.x * 4 + wave;           // 0..639
    const float* src = supp + (size_t)row * DD;
    unsigned short* dst = suppBf + (size_t)row * DD;
    float ss = 0.f;
    #pragma unroll
    for (int i = 0; i < 8; ++i) {
        float4 v = *reinterpret_cast<const float4*>(src + i * 256 + lane * 4);
        uint2 pv = { f2bf2(v.x, v.y), f2bf2(v.z, v.w) };
        *reinterpret_cast<uint2*>(dst + i * 256 + lane * 4) = pv;
        ss += v.x * v.x + v.y * v.y + v.z * v.z + v.w * v.w;
    }
    #pragma unroll
    for (int off = 32; off >= 1; off >>= 1) ss += __shfl_xor(ss, off, 64);
    if (lane == 0) suppSq[row] = ss;
}

// One block per (b,q). Query tile staged in TWO K-halves (LDS 33 KB instead of
// 66 KB) -> ~38.6 KB total LDS -> 4 blocks/CU resident (32 waves = full CU).
// All 1024 blocks resident in one round: staging latency of one block overlaps
// MFMA/DTW of the others. MFMA accumulators persist across the two half-phases.
// Loss is fused: each block atomicAdds its row's CE term into out[0].
__global__ __launch_bounds__(512, 8) void
dist_dtw_kernel(const unsigned short* __restrict__ suppBf, const float* __restrict__ suppSq,
                const float* __restrict__ query, const int* __restrict__ ys,
                float* __restrict__ out)   // out[0] = loss, out+1 = tam (5120 f32)
{
    __shared__ __align__(16) unsigned short sB[TT * LDB];   // 33024 B (half-K tile)
    __shared__ float ssq[96];
    __shared__ float distS[NS][TT][TT];
    __shared__ float tamv[16];

    const int tid  = threadIdx.x;
    const int blk  = blockIdx.x;          // b*128 + q
    const int wave = tid >> 6;            // 0..7 (0..4 = s)
    const int lane = tid & 63;
    const int fr   = lane & 15;
    const int quad = lane >> 4;

    const int qr = tid >> 5;              // staging row 0..15
    const int qc = tid & 31;              // float4 column base
    const float* qsrc = query + (size_t)(blk * TT + qr) * DD;

    // ---- phase 1a: stage query K-half 0 (cols 0..1023), partial norms ----
    {
        float ss = 0.f;
        #pragma unroll
        for (int i = 0; i < 8; ++i) {
            float4 v = *reinterpret_cast<const float4*>(qsrc + (qc + i * 32) * 4);
            uint2 pv = { f2bf2(v.x, v.y), f2bf2(v.z, v.w) };
            *reinterpret_cast<uint2*>(&sB[qr * LDB + (qc + i * 32) * 4]) = pv;
            ss += v.x * v.x + v.y * v.y + v.z * v.z + v.w * v.w;
        }
        #pragma unroll
        for (int off = 16; off >= 1; off >>= 1) ss += __shfl_xor(ss, off, 32);
        if (qc == 0) ssq[80 + qr] = ss;
        if (tid < 80) ssq[tid] = suppSq[(blk >> 7) * (NS * TT) + tid];
    }
    __syncthreads();

    // ---- phase 2a: MFMA over K-half 0; A from L2-hot suppBf, B from LDS ----
    float4v acc0 = {0.f, 0.f, 0.f, 0.f}, acc1 = {0.f, 0.f, 0.f, 0.f};
    const unsigned short* ap =
        suppBf + ((size_t)((blk >> 7) * NS + wave) * TT + fr) * DD + quad * 8;
    const unsigned short* bp = &sB[fr * LDB + quad * 8];
    if (wave < NS) {
        #pragma unroll 8
        for (int k = 0; k < 32; k += 2) {
            short8 a0 = *reinterpret_cast<const short8*>(ap + k * 32);
            short8 a1 = *reinterpret_cast<const short8*>(ap + k * 32 + 32);
            short8 b0 = *reinterpret_cast<const short8*>(bp + k * 32);
            short8 b1 = *reinterpret_cast<const short8*>(bp + k * 32 + 32);
            acc0 = __builtin_amdgcn_mfma_f32_16x16x32_bf16(a0, b0, acc0, 0, 0, 0);
            acc1 = __builtin_amdgcn_mfma_f32_16x16x32_bf16(a1, b1, acc1, 0, 0, 0);
        }
    }
    __syncthreads();   // all MFMA reads of sB done before overwrite

    // ---- phase 1b: stage query K-half 1 (cols 1024..2047), finish norms ----
    {
        float ss = 0.f;
        #pragma unroll
        for (int i = 0; i < 8; ++i) {
            float4 v = *reinterpret_cast<const float4*>(qsrc + 1024 + (qc + i * 32) * 4);
            uint2 pv = { f2bf2(v.x, v.y), f2bf2(v.z, v.w) };
            *reinterpret_cast<uint2*>(&sB[qr * LDB + (qc + i * 32) * 4]) = pv;
            ss += v.x * v.x + v.y * v.y + v.z * v.z + v.w * v.w;
        }
        #pragma unroll
        for (int off = 16; off >= 1; off >>= 1) ss += __shfl_xor(ss, off, 32);
        if (qc == 0) ssq[80 + qr] += ss;
    }
    __syncthreads();

    // ---- phase 2b: MFMA over K-half 1, then epilogue ----
    if (wave < NS) {
        #pragma unroll 8
        for (int k = 32; k < 64; k += 2) {
            short8 a0 = *reinterpret_cast<const short8*>(ap + k * 32);
            short8 a1 = *reinterpret_cast<const short8*>(ap + k * 32 + 32);
            short8 b0 = *reinterpret_cast<const short8*>(bp + (k - 32) * 32);
            short8 b1 = *reinterpret_cast<const short8*>(bp + (k - 32) * 32 + 32);
            acc0 = __builtin_amdgcn_mfma_f32_16x16x32_bf16(a0, b0, acc0, 0, 0, 0);
            acc1 = __builtin_amdgcn_mfma_f32_16x16x32_bf16(a1, b1, acc1, 0, 0, 0);
        }
        // epilogue: dist[s][l][m] = 1 - dot / max(||s_l||*||q_m||, eps)
        float qn = sqrtf(ssq[80 + fr]);
        #pragma unroll
        for (int r = 0; r < 4; ++r) {
            int l = quad * 4 + r;
            float denom = fmaxf(sqrtf(ssq[wave * 16 + l]) * qn, 1e-8f);
            distS[wave][l][fr] = 1.0f - (acc0[r] + acc1[r]) / denom;
        }
    }
    __syncthreads();

    // ---- DTW: anti-diagonal wavefront; wave s, lanes 0..17 dir=0, 32..49 dir=1 ----
    if (wave < NS && (lane & 31) <= 17) {
        const int g   = lane & 31;
        const int dir = lane >> 5;
        const int s   = wave;
        float val = 0.f, vprev = 0.f;
        #pragma unroll
        for (int t = 1; t <= 32; ++t) {
            float left = __shfl_up(val,   1, 32);
            float diag = __shfl_up(vprev, 1, 32);
            int l = t - g;
            if (g >= 1 && l >= 0 && l <= 15) {
                float d = 0.f;
                if (g <= 16) d = dir ? distS[s][15 - l][16 - g] : distS[s][l][g - 1];
                float nv;
                if (l == 0) {
                    nv = left + d;
                } else if (g == 1 || g == 17) {
                    nv = -LAMF * lse2f(lse2f(-diag * LAMI, -left * LAMI), -val * LAMI) + d;
                } else {
                    float lo2 = fminf(diag, left), hi2 = fmaxf(diag, left);
                    nv = lo2 - LAMF * __logf(1.0f + __expf((lo2 - hi2) * LAMI)) + d;
                }
                vprev = val; val = nv;
            }
        }
        if (g == 17) tamv[s * 2 + dir] = val;
    }
    __syncthreads();

    // ---- outputs: tam + fused per-row cross-entropy term ----
    if (tid < NS) {
        out[1 + blk * NS + tid] = 0.5f * (tamv[2 * tid] + tamv[2 * tid + 1]);
    }
    if (tid == 0) {
        float t1v[NS], t2v[NS];
        #pragma unroll
        for (int s = 0; s < NS; ++s) { t1v[s] = tamv[2 * s]; t2v[s] = tamv[2 * s + 1]; }
        const int y = ys[blk];

        float mx1 = -t1v[0], mx2 = -t2v[0];
        #pragma unroll
        for (int s = 1; s < NS; ++s) { mx1 = fmaxf(mx1, -t1v[s]); mx2 = fmaxf(mx2, -t2v[s]); }
        float s1 = 0.f, s2 = 0.f;
        #pragma unroll
        for (int s = 0; s < NS; ++s) { s1 += __expf(-t1v[s] - mx1); s2 += __expf(-t2v[s] - mx2); }
        float lse1  = mx1 + __logf(s1);
        float lse2v = mx2 + __logf(s2);

        float ty1 = t1v[0], ty2 = t2v[0];
        #pragma unroll
        for (int s = 1; s < NS; ++s) { if (y == s) { ty1 = t1v[s]; ty2 = t2v[s]; } }

        float c = 0.5f * ((lse1 + ty1) + (lse2v + ty2));
        atomicAdd(out, c * (1.0f / (float)NROW));
    }
}

extern "C" void kernel_launch(void* const* d_in, const int* in_sizes, int n_in,
                              void* d_out, int out_size, void* d_ws, size_t ws_size,
                              hipStream_t stream) {
    const float* supp  = (const float*)d_in[0];
    const float* query = (const float*)d_in[1];
    const int*   ys    = (const int*)d_in[2];
    float* out = (float*)d_out;

    float* suppSq = (float*)d_ws;                              // 640 f32
    unsigned short* suppBf = (unsigned short*)(suppSq + NSROW);// 640*2048 bf16

    preproc_supp<<<NSROW / 4, 256, 0, stream>>>(supp, suppBf, suppSq, out);
    dist_dtw_kernel<<<NROW, 512, 0, stream>>>(suppBf, suppSq, query, ys, out);
}